// Round 2
// baseline (757.386 us; speedup 1.0000x reference)
//
#include <hip/hip_runtime.h>
#include <stdint.h>

#define FEAT 512
#define HID  256
#define TILE 64
#define PART 512   // fused_main grid = number of partials
#define S1   64    // reduce_stage1 grid (PART/8)

typedef __attribute__((ext_vector_type(8))) short   short8;
typedef __attribute__((ext_vector_type(4))) float   floatx4;
typedef unsigned int u32;
#define AS1 __attribute__((address_space(1)))
#define AS3 __attribute__((address_space(3)))

__device__ inline void gl_lds16(const void* g, void* l){
  __builtin_amdgcn_global_load_lds((const AS1 u32*)g, (AS3 u32*)l, 16, 0, 0);
}

__device__ inline unsigned short f2bf(float x){
  union { float f; uint32_t u; } v; v.f = x;
  uint32_t u = v.u;
  u += 0x7FFFu + ((u >> 16) & 1u);      // round-to-nearest-even
  return (unsigned short)(u >> 16);
}
__device__ inline float bf2f(unsigned short h){
  union { uint32_t u; float f; } v; v.u = ((uint32_t)h) << 16;
  return v.f;
}
__device__ inline float sigm_f(float x){ return 1.f/(1.f + __expf(-x)); }
__device__ inline float tanh_f(float x){ return 2.f/(1.f + __expf(-2.f*x)) - 1.f; }

// ---------------------------------------------------------------------------
// prep: build unified 32-round weight blob (16 KB per round, bf16, MFMA
// B-fragment order). Rounds 0..15: W1 kb-slices. Rounds 16..31: r2=nh*8+kb,
// first 8KB = Wa half-slice, second 8KB = Wb half-slice.
// frag: dst[r*8192 + slot*8 + j]; within W1 round slot=(nt*64+lane);
// within Wab round slot = half*512 + nt2*64 + lane.
// value = W[kb*32 + (lane>>4)*8 + j][col], col = nt*16 + (lane&15).
// ---------------------------------------------------------------------------
__global__ void prep_weights(const float* __restrict__ W1, const float* __restrict__ Wa,
                             const float* __restrict__ Wb, unsigned short* __restrict__ blob){
  int t = blockIdx.x*256 + threadIdx.x;   // 32768 total
  if (t >= 32768) return;
  int r = t >> 10, s = t & 1023;
  int lane = s & 63, l15 = lane & 15, quad = lane >> 4;
  const float* src; int col, row0;
  if (r < 16){
    int nt = s >> 6;
    src = W1; col = nt*16 + l15; row0 = r*32 + quad*8;
  } else {
    int r2 = r - 16, nh = r2 >> 3, kb = r2 & 7;
    int half = s >> 9, nt2 = (s >> 6) & 7;
    src = half ? Wb : Wa;
    col = (nh*8 + nt2)*16 + l15; row0 = kb*32 + quad*8;
  }
  unsigned short* d = blob + (size_t)t*8;
  const float*   sp = src + (size_t)row0*HID + col;
  #pragma unroll
  for (int j = 0; j < 8; ++j) d[j] = f2bf(sp[(size_t)j*HID]);
}

// ---------------------------------------------------------------------------
// fused_main v2: double-buffered async weight staging (1 barrier/round),
// software-pipelined x loads. Per 64-token tile: h=relu(x@W1+b1);
// a=tanh(h@Wa+ba); b=sigm(h@Wb+bb); s=(a*b)@Wc+bc; online softmax (m,l,g).
// ---------------------------------------------------------------------------
__global__ __launch_bounds__(256, 2) void fused_main(
    const float* __restrict__ x,
    const float* __restrict__ b1, const float* __restrict__ ba,
    const float* __restrict__ bb, const float* __restrict__ Wc,
    const float* __restrict__ bc,
    const unsigned short* __restrict__ blob,
    float* __restrict__ s_buf, float* __restrict__ partials, int ntiles)
{
  __shared__ alignas(16) unsigned short Hs[64][264];   // 33.8 KB
  __shared__ alignas(16) unsigned short Ws[2][8192];   // 32 KB double buffer
  __shared__ float pbuf[4][16];

  const int tid  = threadIdx.x;
  const int wave = tid >> 6, lane = tid & 63;
  const int quad = lane >> 4, l15 = lane & 15;

  // stage one 16KB round into Ws[buf]: 4 waves x 4 chunks x (64 lanes x 16B)
  auto stage = [&](int rnd, int buf){
    #pragma unroll
    for (int c = 0; c < 4; ++c){
      const unsigned short* gp = blob + (size_t)rnd*8192 + (wave*4 + c)*512 + lane*8;
      gl_lds16((const void*)gp, (void*)&Ws[buf][(wave*4 + c)*512]);
    }
  };

  // loop-invariant preloads
  float b1r[16], bar[16], bbr[16], wcr[16];
  #pragma unroll
  for (int i = 0; i < 16; ++i){
    int ci = i*16 + l15;
    b1r[i] = b1[ci]; bar[i] = ba[ci]; bbr[i] = bb[ci]; wcr[i] = Wc[ci];
  }
  const float bcv = bc[0];

  float m_run = -INFINITY, l_run = 0.f;
  float g0 = 0.f, g1 = 0.f, g2 = 0.f, g3 = 0.f;

  // prefetch first x chunk + first weight round
  float4 xa = {0,0,0,0}, xb = {0,0,0,0};
  if (blockIdx.x < ntiles){
    const float* xr = x + (size_t)(blockIdx.x*TILE + wave*16 + l15)*FEAT + quad*8;
    xa = *(const float4*)xr; xb = *(const float4*)(xr + 4);
  }
  stage(0, 0);
  __syncthreads();

  #pragma unroll 1
  for (int t = blockIdx.x; t < ntiles; t += gridDim.x){
    const int tokw = t*TILE + wave*16;
    const float* xrow = x + (size_t)(tokw + l15)*FEAT + quad*8;

    // ---------------- GEMM1: h = relu(x @ W1 + b1), K=512 ----------------
    floatx4 acc[16];
    #pragma unroll
    for (int nt = 0; nt < 16; ++nt){
      float bv = b1r[nt];
      floatx4 tmp = {bv, bv, bv, bv};
      acc[nt] = tmp;
    }
    #pragma unroll 2
    for (int kb = 0; kb < 16; ++kb){
      stage(kb + 1, (kb + 1) & 1);                 // kb=15 stages round 16 (G2 first)
      float4 xa_n, xb_n;
      if (kb < 15){
        const float* xp = xrow + (kb + 1)*32;
        xa_n = *(const float4*)xp; xb_n = *(const float4*)(xp + 4);
      }
      union { short8 v; unsigned short u[8]; } af;
      af.u[0]=f2bf(xa.x); af.u[1]=f2bf(xa.y); af.u[2]=f2bf(xa.z); af.u[3]=f2bf(xa.w);
      af.u[4]=f2bf(xb.x); af.u[5]=f2bf(xb.y); af.u[6]=f2bf(xb.z); af.u[7]=f2bf(xb.w);
      const unsigned short* wsb = Ws[kb & 1];
      #pragma unroll
      for (int nt = 0; nt < 16; ++nt){
        short8 bfv = *(const short8*)&wsb[nt*512 + lane*8];
        acc[nt] = __builtin_amdgcn_mfma_f32_16x16x32_bf16(af.v, bfv, acc[nt], 0, 0, 0);
      }
      __syncthreads();
      if (kb < 15){ xa = xa_n; xb = xb_n; }
    }
    // epilogue: relu -> bf16 h into own wave strip (wave-private, no barrier)
    #pragma unroll
    for (int nt = 0; nt < 16; ++nt){
      #pragma unroll
      for (int r = 0; r < 4; ++r){
        float hv = fmaxf(acc[nt][r], 0.f);
        Hs[wave*16 + quad*4 + r][nt*16 + l15] = f2bf(hv);
      }
    }

    // prefetch next tile's first x chunk (16 G2 rounds of latency cover)
    {
      int tn = t + gridDim.x;
      if (tn < ntiles){
        const float* xr = x + (size_t)(tn*TILE + wave*16 + l15)*FEAT + quad*8;
        xa = *(const float4*)xr; xb = *(const float4*)(xr + 4);
      }
    }

    // ---- GEMM2: a=tanh(h@Wa+ba), b=sigm(h@Wb+bb), s=(a*b)@Wc+bc, K=256 ----
    float sp0 = 0.f, sp1 = 0.f, sp2 = 0.f, sp3 = 0.f;
    #pragma unroll
    for (int nh = 0; nh < 2; ++nh){
      floatx4 aacc[8], bacc[8];
      #pragma unroll
      for (int nt2 = 0; nt2 < 8; ++nt2){
        float av = bar[nh*8 + nt2], bv = bbr[nh*8 + nt2];
        floatx4 ta = {av, av, av, av}; aacc[nt2] = ta;
        floatx4 tb = {bv, bv, bv, bv}; bacc[nt2] = tb;
      }
      #pragma unroll 2
      for (int kb = 0; kb < 8; ++kb){
        const int r = nh*8 + kb;
        stage((r == 15) ? 0 : (17 + r), (r + 1) & 1);  // r=15 wraps to round 0 (next tile)
        short8 af2 = *(const short8*)&Hs[wave*16 + l15][kb*32 + quad*8];
        const unsigned short* wsb = Ws[r & 1];
        #pragma unroll
        for (int nt2 = 0; nt2 < 8; ++nt2){
          short8 bA = *(const short8*)&wsb[nt2*512 + lane*8];
          short8 bB = *(const short8*)&wsb[4096 + nt2*512 + lane*8];
          aacc[nt2] = __builtin_amdgcn_mfma_f32_16x16x32_bf16(af2, bA, aacc[nt2], 0, 0, 0);
          bacc[nt2] = __builtin_amdgcn_mfma_f32_16x16x32_bf16(af2, bB, bacc[nt2], 0, 0, 0);
        }
        __syncthreads();
      }
      #pragma unroll
      for (int nt2 = 0; nt2 < 8; ++nt2){
        float wcv = wcr[nh*8 + nt2];
        sp0 += tanh_f(aacc[nt2][0]) * sigm_f(bacc[nt2][0]) * wcv;
        sp1 += tanh_f(aacc[nt2][1]) * sigm_f(bacc[nt2][1]) * wcv;
        sp2 += tanh_f(aacc[nt2][2]) * sigm_f(bacc[nt2][2]) * wcv;
        sp3 += tanh_f(aacc[nt2][3]) * sigm_f(bacc[nt2][3]) * wcv;
      }
    }
    // reduce s across the 16 lanes of each l15-group (rows = quad*4+r)
    #pragma unroll
    for (int mk = 1; mk < 16; mk <<= 1){
      sp0 += __shfl_xor(sp0, mk, 64);
      sp1 += __shfl_xor(sp1, mk, 64);
      sp2 += __shfl_xor(sp2, mk, 64);
      sp3 += __shfl_xor(sp3, mk, 64);
    }
    float s0 = sp0 + bcv, s1 = sp1 + bcv, s2 = sp2 + bcv, s3 = sp3 + bcv;
    if (l15 == 0){
      float* sb = s_buf + tokw + quad*4;
      sb[0] = s0; sb[1] = s1; sb[2] = s2; sb[3] = s3;
    }
    // online softmax update (per wave)
    float tmax = fmaxf(fmaxf(s0, s1), fmaxf(s2, s3));
    tmax = fmaxf(tmax, __shfl_xor(tmax, 16, 64));
    tmax = fmaxf(tmax, __shfl_xor(tmax, 32, 64));
    float m_new = fmaxf(m_run, tmax);
    float alpha = __expf(m_run - m_new);
    float p0 = __expf(s0 - m_new), p1 = __expf(s1 - m_new);
    float p2 = __expf(s2 - m_new), p3 = __expf(s3 - m_new);
    float psum = p0 + p1 + p2 + p3;
    psum += __shfl_xor(psum, 16, 64);
    psum += __shfl_xor(psum, 32, 64);
    l_run = l_run*alpha + psum;
    m_run = m_new;
    if (l15 == 0){
      pbuf[wave][quad*4+0] = p0; pbuf[wave][quad*4+1] = p1;
      pbuf[wave][quad*4+2] = p2; pbuf[wave][quad*4+3] = p3;
    }
    g0 *= alpha; g1 *= alpha; g2 *= alpha; g3 *= alpha;
    #pragma unroll
    for (int rw = 0; rw < 16; ++rw){
      float pr = pbuf[wave][rw];
      const unsigned short* hp = &Hs[wave*16 + rw][lane*4];
      g0 += pr*bf2f(hp[0]); g1 += pr*bf2f(hp[1]);
      g2 += pr*bf2f(hp[2]); g3 += pr*bf2f(hp[3]);
    }
  }

  // ---- combine 4 waves -> per-workgroup partial {M, L, g[256]} ----
  __syncthreads();
  float* fred = (float*)(&Ws[0][0]);
  if (lane == 0) fred[wave] = m_run;
  __syncthreads();
  float M = fmaxf(fmaxf(fred[0], fred[1]), fmaxf(fred[2], fred[3]));
  float sc = (m_run == -INFINITY) ? 0.f : __expf(m_run - M);
  if (lane == 0) fred[4 + wave] = l_run * sc;
  fred[8 + wave*256 + lane*4 + 0] = g0*sc;
  fred[8 + wave*256 + lane*4 + 1] = g1*sc;
  fred[8 + wave*256 + lane*4 + 2] = g2*sc;
  fred[8 + wave*256 + lane*4 + 3] = g3*sc;
  __syncthreads();
  float gsum = fred[8 + 0*256 + tid] + fred[8 + 1*256 + tid]
             + fred[8 + 2*256 + tid] + fred[8 + 3*256 + tid];
  float* P = partials + (size_t)blockIdx.x*258;
  if (tid == 0){ P[0] = M; P[1] = fred[4] + fred[5] + fred[6] + fred[7]; }
  P[2 + tid] = gsum;
}

// ---------------------------------------------------------------------------
// reduce_stage1: 64 WGs, each merges 8 partials -> 1 (online-softmax merge).
// ---------------------------------------------------------------------------
__global__ void reduce_stage1(const float* __restrict__ partials, float* __restrict__ p2){
  int j = blockIdx.x, t = threadIdx.x;
  const float* base = partials + (size_t)j*8*258;
  float m = -INFINITY;
  #pragma unroll
  for (int k = 0; k < 8; ++k) m = fmaxf(m, base[k*258]);
  float w[8]; float l = 0.f;
  #pragma unroll
  for (int k = 0; k < 8; ++k){
    w[k] = __expf(base[k*258] - m);
    l += base[k*258 + 1] * w[k];
  }
  float g = 0.f;
  #pragma unroll
  for (int k = 0; k < 8; ++k) g += base[k*258 + 2 + t] * w[k];
  float* o = p2 + (size_t)j*258;
  if (t == 0){ o[0] = m; o[1] = l; }
  o[2 + t] = g;
}

// ---------------------------------------------------------------------------
// reduce_heads: combine S1 partials -> M, L, global_feat; then hr/cls/reg.
// ---------------------------------------------------------------------------
__global__ void reduce_heads(const float* __restrict__ p2,
    const float* __restrict__ Wr,   const float* __restrict__ br,
    const float* __restrict__ Wcls, const float* __restrict__ bcls,
    const float* __restrict__ Wreg, const float* __restrict__ breg,
    float* __restrict__ out, float* __restrict__ ML, int ntok)
{
  __shared__ float red[256];
  __shared__ float scw[S1];
  __shared__ float gf[256];
  __shared__ float hr[256];
  int t = threadIdx.x;

  float lm = (t < S1) ? p2[(size_t)t*258] : -INFINITY;
  red[t] = lm; __syncthreads();
  for (int s = 128; s > 0; s >>= 1){ if (t < s) red[t] = fmaxf(red[t], red[t+s]); __syncthreads(); }
  float M = red[0];
  __syncthreads();

  float ll = 0.f;
  if (t < S1){
    float w = __expf(p2[(size_t)t*258] - M);
    scw[t] = w;
    ll = p2[(size_t)t*258 + 1] * w;
  }
  red[t] = ll; __syncthreads();
  for (int s = 128; s > 0; s >>= 1){ if (t < s) red[t] += red[t+s]; __syncthreads(); }
  float L = red[0];
  __syncthreads();

  float g = 0.f;
  #pragma unroll 16
  for (int i = 0; i < S1; ++i) g += p2[(size_t)i*258 + 2 + t] * scw[i];
  float gfv = g / L;
  gf[t] = gfv;
  out[ntok + t] = gfv;
  if (t == 0){ ML[0] = M; ML[1] = 1.f / L; }
  __syncthreads();

  float h = br[t];
  #pragma unroll 8
  for (int c = 0; c < 256; ++c) h += gf[c] * Wr[c*256 + t];
  h = fmaxf(h, 0.f);
  hr[t] = h; __syncthreads();

  if (t < 33){
    float v = bcls[t];
    #pragma unroll 8
    for (int j = 0; j < 256; ++j) v += hr[j] * Wcls[j*33 + t];
    out[ntok + 256 + t] = v;
  }
  if (t < 55){
    float v = breg[t];
    #pragma unroll 8
    for (int j = 0; j < 256; ++j) v += hr[j] * Wreg[j*55 + t];
    out[ntok + 289 + t] = v;
  }
}

// ---------------------------------------------------------------------------
__global__ void finalize_A(const float* __restrict__ s_buf, const float* __restrict__ ML,
                           float* __restrict__ out, int n4){
  int i = blockIdx.x*256 + threadIdx.x;
  if (i < n4){
    float M = ML[0], Li = ML[1];
    float4 s = ((const float4*)s_buf)[i];
    float4 o;
    o.x = __expf(s.x - M)*Li; o.y = __expf(s.y - M)*Li;
    o.z = __expf(s.z - M)*Li; o.w = __expf(s.w - M)*Li;
    ((float4*)out)[i] = o;
  }
}

// ---------------------------------------------------------------------------
extern "C" void kernel_launch(void* const* d_in, const int* in_sizes, int n_in,
                              void* d_out, int out_size, void* d_ws, size_t ws_size,
                              hipStream_t stream){
  (void)n_in; (void)out_size; (void)ws_size;
  const float* x    = (const float*)d_in[0];
  const float* W1   = (const float*)d_in[1];
  const float* b1   = (const float*)d_in[2];
  const float* Wa   = (const float*)d_in[3];
  const float* ba   = (const float*)d_in[4];
  const float* Wb   = (const float*)d_in[5];
  const float* bb   = (const float*)d_in[6];
  const float* Wc   = (const float*)d_in[7];
  const float* bc   = (const float*)d_in[8];
  const float* Wr   = (const float*)d_in[9];
  const float* br   = (const float*)d_in[10];
  const float* Wcls = (const float*)d_in[11];
  const float* bcls = (const float*)d_in[12];
  const float* Wreg = (const float*)d_in[13];
  const float* breg = (const float*)d_in[14];
  float* out = (float*)d_out;

  const int ntok   = in_sizes[0] / FEAT;   // 200000
  const int ntiles = ntok / TILE;          // 3125

  char* ws = (char*)d_ws;
  float* s_buf = (float*)ws;
  size_t off = (size_t)ntok * 4;                                  // 800000
  float* partials = (float*)(ws + off); off += (size_t)PART*258*4;  // 528384
  float* p2       = (float*)(ws + off); off += (size_t)S1*258*4;    // 66048
  float* ML       = (float*)(ws + off); off += 16;
  unsigned short* blob = (unsigned short*)(ws + off); off += 32*8192*2; // 512 KB
  // total ~1.92 MB

  prep_weights<<<128, 256, 0, stream>>>(W1, Wa, Wb, blob);
  fused_main<<<PART, 256, 0, stream>>>(x, b1, ba, bb, Wc, bc, blob,
                                       s_buf, partials, ntiles);
  reduce_stage1<<<S1, 256, 0, stream>>>(partials, p2);
  reduce_heads<<<1, 256, 0, stream>>>(p2, Wr, br, Wcls, bcls, Wreg, breg,
                                      out, ML, ntok);
  finalize_A<<<(ntok/4 + 255)/256, 256, 0, stream>>>(s_buf, ML, out, ntok/4);
}